// Round 3
// baseline (262.678 us; speedup 1.0000x reference)
//
#include <hip/hip_runtime.h>
#include <hip/hip_fp16.h>

#define NEG_SLOPE 0.2f
#define BN_EPS 1e-5f

constexpr int D = 64;   // feature dim
constexpr int H = 4;    // heads

typedef _Float16 half2_t __attribute__((ext_vector_type(2)));
typedef _Float16 half4_t __attribute__((ext_vector_type(4)));
typedef _Float16 half8_t __attribute__((ext_vector_type(8)));
typedef float f32x4_t __attribute__((ext_vector_type(4)));
typedef int i32x4 __attribute__((ext_vector_type(4)));  // native vec for nontemporal builtins

// 16-B edge record: {src, pad, w[4]}; w = per-edge softmax numerators (4 heads)
union Rec {
    i32x4 i4;
    struct { int idx; int pad; half4_t w; } f;
};

#define MFMA16(a, b, c) __builtin_amdgcn_mfma_f32_16x16x32_f16(a, b, c, 0, 0, 0)

#if __has_builtin(__builtin_amdgcn_fdot2)
#define FDOT2(a, b, c) __builtin_amdgcn_fdot2((a), (b), (c), false)
#else
#define FDOT2(a, b, c) ((c) + (float)(a)[0] * (float)(b)[0] + (float)(a)[1] * (float)(b)[1])
#endif

__device__ inline half2_t h2cast(unsigned int u) { return __builtin_bit_cast(half2_t, u); }

__device__ inline float lrelu(float v) { return (v >= 0.f) ? v : NEG_SLOPE * v; }

// load 8 consecutive fp32, split into fp16 hi + lo halves (hi+lo ~ fp32)
__device__ inline void split8(const float* p, bool ok, half8_t& hi, half8_t& lo) {
    float f[8];
    if (ok) {
        float4 a = *(const float4*)p;
        float4 b = *(const float4*)(p + 4);
        f[0] = a.x; f[1] = a.y; f[2] = a.z; f[3] = a.w;
        f[4] = b.x; f[5] = b.y; f[6] = b.z; f[7] = b.w;
    } else {
        #pragma unroll
        for (int j = 0; j < 8; j++) f[j] = 0.f;
    }
    #pragma unroll
    for (int j = 0; j < 8; j++) {
        _Float16 h = (_Float16)f[j];
        hi[j] = h;
        lo[j] = (_Float16)(f[j] - (float)h);
    }
}

// Fused MFMA node kernel, 32 nodes/block.
// ROUND-3 CHANGES:
//  (a) BOTH rank-atomics go to the slice keyed by the ISSUING block's XCD
//      (p = blockIdx&7). Previously e1's slice was (blockIdx+3)&7 -> those
//      deg8 lines ping-ponged between two XCDs' L2s (R2 counters: WRITE_SIZE
//      54.7 MB vs 31 MB logical = bounce writebacks; multi-thousand-cycle
//      atomic latency at the FRONT of the vmcnt FIFO stalled every
//      subsequent waitcnt -> all pipes <15% busy).
//  (b) h_lds aliases x1hi/x1lo (dead after stage-B fragment loads; extra
//      __syncthreads() guards the WAR) -> LDS 26.1 KB -> 16.9 KB -> 8
//      resident blocks/CU instead of 6.
__global__ __launch_bounds__(256) void k_node(
    const float* __restrict__ x,
    const float* __restrict__ W_lin, const float* __restrict__ b_lin,
    const float* __restrict__ prelu_w, const float* __restrict__ W_gat,
    const float* __restrict__ att_src, const float* __restrict__ att_dst,
    _Float16* __restrict__ hh, float* __restrict__ asrc_ws,
    float* __restrict__ adst_ws, const int* __restrict__ ei,
    int* __restrict__ deg8, int* __restrict__ rank, int N, int E)
{
    __shared__ _Float16 smem[32 * 264];   // 16.9 KB total (h_lds aliases x1)
    _Float16* __restrict__ h_lds = smem;           // [32][264] after re-barrier
    _Float16* __restrict__ x1hi  = smem;           // [32][72]
    _Float16* __restrict__ x1lo  = smem + 32 * 72; // [32][72]

    const int t = threadIdx.x;
    const int w = t >> 6;    // wave id == head
    const int l = t & 63;
    const int li = l & 15;
    const int lq = l >> 4;
    const int base = blockIdx.x * 32;
    const int nvalid = min(32, N - base);

    // ---- prelude phase 1: issue both rank-atomics (XCD-local slices) ----
    const int nthreads = gridDim.x * 256;
    const int e0 = blockIdx.x * 256 + t;
    const int e1 = e0 + nthreads;
    const bool v0 = e0 < E;
    const bool v1 = e1 < E;
    const int xcd = blockIdx.x & 7;
    int r0v = 0, r1v = 0;
    {
        int d0 = 0, d1 = 0;
        if (v0) d0 = ei[E + e0];
        if (v1) d1 = ei[E + e1];
        if (v0) r0v = atomicAdd(&deg8[xcd * N + d0], 1);
        if (v1) r1v = atomicAdd(&deg8[xcd * N + d1], 1);
    }

    // ---- stage A: MFMA x @ W_lin^T for cols 16w..16w+15, 2 m-tiles ----
    f32x4_t accA[2] = {};
    {
        half8_t blh[2], bll[2];
        const int n = 16 * w + li;
        #pragma unroll
        for (int ks = 0; ks < 2; ks++)
            split8(W_lin + n * 64 + 32 * ks + 8 * lq, true, blh[ks], bll[ks]);
        #pragma unroll
        for (int mt = 0; mt < 2; mt++) {
            const int row = base + 16 * mt + li;
            const bool ok = row < N;
            #pragma unroll
            for (int ks = 0; ks < 2; ks++) {
                half8_t ah, al;
                split8(x + (size_t)row * 64 + 32 * ks + 8 * lq, ok, ah, al);
                accA[mt] = MFMA16(ah, blh[ks], accA[mt]);
                accA[mt] = MFMA16(al, blh[ks], accA[mt]);
                accA[mt] = MFMA16(ah, bll[ks], accA[mt]);
            }
        }
    }

    // ---- prelude phase 3: store ranks (atomic returns arrived long ago) ----
    if (v0) rank[e0] = r0v;
    if (v1) rank[e1] = r1v;

    // epilogue A: +bias, prelu, split to fp16 hi/lo in LDS
    {
        const int n = 16 * w + li;
        const float bl = b_lin[n];
        const float pw = prelu_w[n];
        #pragma unroll
        for (int mt = 0; mt < 2; mt++) {
            #pragma unroll
            for (int r = 0; r < 4; r++) {
                const int m = 16 * mt + lq * 4 + r;
                float v = accA[mt][r] + bl;
                v = (v >= 0.f) ? v : pw * v;
                _Float16 hi = (_Float16)v;
                x1hi[m * 72 + n] = hi;
                x1lo[m * 72 + n] = (_Float16)(v - (float)hi);
            }
        }
    }
    __syncthreads();

    // ---- stage B: MFMA x1 @ W_gat^T for cols 64w..64w+63, 2 m-tiles ----
    half8_t xah[2][2], xal[2][2];
    #pragma unroll
    for (int mt = 0; mt < 2; mt++) {
        #pragma unroll
        for (int ks = 0; ks < 2; ks++) {
            const int off = (16 * mt + li) * 72 + 32 * ks + 8 * lq;
            xah[mt][ks] = *(const half8_t*)(&x1hi[off]);
            xal[mt][ks] = *(const half8_t*)(&x1lo[off]);
        }
    }
    f32x4_t accB[2][4] = {};
    #pragma unroll
    for (int nt = 0; nt < 4; nt++) {
        half8_t wh[2], wl[2];
        const int c = 64 * w + 16 * nt + li;
        #pragma unroll
        for (int ks = 0; ks < 2; ks++)
            split8(W_gat + (size_t)c * 64 + 32 * ks + 8 * lq, true, wh[ks], wl[ks]);
        #pragma unroll
        for (int mt = 0; mt < 2; mt++) {
            #pragma unroll
            for (int ks = 0; ks < 2; ks++) {
                accB[mt][nt] = MFMA16(xah[mt][ks], wh[ks], accB[mt][nt]);
                accB[mt][nt] = MFMA16(xal[mt][ks], wh[ks], accB[mt][nt]);
                accB[mt][nt] = MFMA16(xah[mt][ks], wl[ks], accB[mt][nt]);
            }
        }
    }

    // ---- attention dots from registers: a[n][w] = sum_d h[n][w][d]*att[w][d]
    {
        float asv[4], adv[4];
        #pragma unroll
        for (int nt = 0; nt < 4; nt++) {
            const int c = 64 * w + 16 * nt + li;
            asv[nt] = att_src[c];
            adv[nt] = att_dst[c];
        }
        #pragma unroll
        for (int mt = 0; mt < 2; mt++) {
            #pragma unroll
            for (int r = 0; r < 4; r++) {
                float s = 0.f, dsum = 0.f;
                #pragma unroll
                for (int nt = 0; nt < 4; nt++) {
                    s += accB[mt][nt][r] * asv[nt];
                    dsum += accB[mt][nt][r] * adv[nt];
                }
                #pragma unroll
                for (int off = 1; off < 16; off <<= 1) {
                    s += __shfl_xor(s, off, 64);
                    dsum += __shfl_xor(dsum, off, 64);
                }
                if (li == 0) {
                    const int m = 16 * mt + lq * 4 + r;
                    if (m < nvalid) {
                        asrc_ws[(size_t)(base + m) * H + w] = s;
                        adst_ws[(size_t)(base + m) * H + w] = dsum;
                    }
                }
            }
        }
    }

    // WAR guard: all waves must finish their x1 ds_reads before h_lds
    // (same LDS bytes) is overwritten.
    __syncthreads();

    // ---- h -> LDS in padded [m][264] layout, then coalesced global write ----
    #pragma unroll
    for (int mt = 0; mt < 2; mt++) {
        #pragma unroll
        for (int nt = 0; nt < 4; nt++) {
            #pragma unroll
            for (int r = 0; r < 4; r++) {
                const int m = 16 * mt + lq * 4 + r;
                const int d = 16 * nt + li;
                h_lds[m * 264 + d * 4 + w] = (_Float16)accB[mt][nt][r];
            }
        }
    }
    __syncthreads();
    {
        const int chunks = nvalid * 32;  // 8 halves (16B) per chunk
        const uint4* src = (const uint4*)h_lds;
        uint4* dst = (uint4*)(hh + (size_t)base * 256);
        for (int i = t; i < chunks; i += 256) {
            int row = i >> 5;
            int col = i & 31;
            dst[i] = src[row * 33 + col];  // padded row = 33 uint4
        }
    }
}

// offsets: fold the 8 slices (exclusive prefix over p -> pref8, total -> deg),
// then per-block exclusive scan + one atomicAdd for the block's recs base.
__global__ __launch_bounds__(256) void k_offsets(const int* __restrict__ deg8,
                                                 int* __restrict__ pref8,
                                                 int* __restrict__ deg,
                                                 int* __restrict__ gcount,
                                                 int* __restrict__ offs, int N) {
    __shared__ int sm[256];
    __shared__ int sbase;
    int t = threadIdx.x;
    int idx = blockIdx.x * 256 + t;
    int v = 0;
    if (idx < N) {
        #pragma unroll
        for (int p = 0; p < 8; p++) {
            int c = deg8[p * N + idx];
            pref8[p * N + idx] = v;
            v += c;
        }
        deg[idx] = v;
    }
    sm[t] = v;
    __syncthreads();
    for (int off = 1; off < 256; off <<= 1) {
        int w = (t >= off) ? sm[t - off] : 0;
        __syncthreads();
        sm[t] += w;
        __syncthreads();
    }
    if (t == 255) sbase = atomicAdd(gcount, sm[255]);
    __syncthreads();
    if (idx < N) offs[idx] = sbase + sm[t] - v;  // exclusive within block + base
}

// atomic-free permute-scatter: pos = offs[dst] + pref8[p][dst] + rank.
// p must reproduce k_node's slice choice: k_node block b histograms edges
// e0 (group g=b) and e1 (group g=b+NB) both into slice b&7. So for edge e
// with g=e>>8: p = (g < NB ? g : g-NB) & 7.
__global__ __launch_bounds__(256) void k_fill(const int* __restrict__ ei,
                                              const int* __restrict__ offs,
                                              const int* __restrict__ pref8,
                                              const int* __restrict__ rank,
                                              const float* __restrict__ asrc,
                                              const float* __restrict__ adst,
                                              i32x4* __restrict__ recs,
                                              int N, int E, int NB) {
    int e = blockIdx.x * 256 + threadIdx.x;
    if (e >= E) return;
    int s = ei[e];
    int d = ei[E + e];
    int g = e >> 8;
    int p = (g < NB ? g : g - NB) & 7;
    int r0 = rank[e];
    int pos = offs[d] + pref8[p * N + d] + r0;
    float4 a = *(const float4*)(asrc + (size_t)s * H);
    float4 b = *(const float4*)(adst + (size_t)d * H);
    Rec r;
    r.f.idx = s;
    r.f.pad = 0;
    r.f.w[0] = (_Float16)__expf(lrelu(a.x + b.x));
    r.f.w[1] = (_Float16)__expf(lrelu(a.y + b.y));
    r.f.w[2] = (_Float16)__expf(lrelu(a.z + b.z));
    r.f.w[3] = (_Float16)__expf(lrelu(a.w + b.w));
    recs[pos] = r.i4;
}

// process one edge pair (A,B) with packed fp16 math:
// v_perm builds (wA_h, wB_h) / (hA_h, hB_h) half2 pairs, v_dot2_f32_f16
// does den_h += wA+wB and acc_h += wA*hA + wB*hB (fp16 mul, fp32 accum --
// numerically identical to the old cvt+fma path, half the VALU ops).
__device__ inline void edge_pair(const i32x4 ra, const i32x4 rb,
                                 const uint2 ha, const uint2 hb,
                                 float& den0, float& den1, float& den2, float& den3,
                                 float& acc0, float& acc1, float& acc2, float& acc3)
{
    const half2_t one2 = h2cast(0x3C003C00u);
    unsigned int wp0 = __builtin_amdgcn_perm((unsigned int)rb.z, (unsigned int)ra.z, 0x05040100u);
    unsigned int wp1 = __builtin_amdgcn_perm((unsigned int)rb.z, (unsigned int)ra.z, 0x07060302u);
    unsigned int wp2 = __builtin_amdgcn_perm((unsigned int)rb.w, (unsigned int)ra.w, 0x05040100u);
    unsigned int wp3 = __builtin_amdgcn_perm((unsigned int)rb.w, (unsigned int)ra.w, 0x07060302u);
    unsigned int hp0 = __builtin_amdgcn_perm(hb.x, ha.x, 0x05040100u);
    unsigned int hp1 = __builtin_amdgcn_perm(hb.x, ha.x, 0x07060302u);
    unsigned int hp2 = __builtin_amdgcn_perm(hb.y, ha.y, 0x05040100u);
    unsigned int hp3 = __builtin_amdgcn_perm(hb.y, ha.y, 0x07060302u);
    den0 = FDOT2(h2cast(wp0), one2, den0);
    den1 = FDOT2(h2cast(wp1), one2, den1);
    den2 = FDOT2(h2cast(wp2), one2, den2);
    den3 = FDOT2(h2cast(wp3), one2, den3);
    acc0 = FDOT2(h2cast(wp0), h2cast(hp0), acc0);
    acc1 = FDOT2(h2cast(wp1), h2cast(hp1), acc1);
    acc2 = FDOT2(h2cast(wp2), h2cast(hp2), acc2);
    acc3 = FDOT2(h2cast(wp3), h2cast(hp3), acc3);
}

// ---- fused softmax + aggregation: one wave per dst node ----
// 8-wide unrolled gather loop (8 recs + 8 h-rows in flight per wave) with a
// CLAMPED final iteration (w zeroed for k>=deg) -- no serial 1-wide tail
// whose dependent rec->gather chains were pure latency. recs are streamed
// once -> nontemporal loads keep them from evicting the 16x-reused hh lines.
// NO BN-stat atomics here: round-1 showed 6.4M contended atomics onto 64
// cache lines throttle the kernel 2.6x (atomic-serialization floor).
__global__ __launch_bounds__(256) void k_agg(
    const float* __restrict__ asrc, const float* __restrict__ adst,
    const int* __restrict__ offs, const int* __restrict__ deg,
    const i32x4* __restrict__ recs, const uint2* __restrict__ hh2,
    float* __restrict__ out, int N)
{
    int wid = (blockIdx.x * 256 + threadIdx.x) >> 6;
    int lane = threadIdx.x & 63;
    if (wid >= N) return;
    const int i = wid;

    float4 b = *(const float4*)(adst + (size_t)i * H);
    float4 a0 = *(const float4*)(asrc + (size_t)i * H);
    float ws0 = __expf(lrelu(a0.x + b.x));
    float ws1 = __expf(lrelu(a0.y + b.y));
    float ws2 = __expf(lrelu(a0.z + b.z));
    float ws3 = __expf(lrelu(a0.w + b.w));

    const int beg = __builtin_amdgcn_readfirstlane(offs[i]);
    const int dg  = __builtin_amdgcn_readfirstlane(deg[i]);

    // self-loop contribution
    float den0 = ws0, den1 = ws1, den2 = ws2, den3 = ws3;
    float acc0, acc1, acc2, acc3;
    {
        uint2 hv = hh2[(size_t)i * D + lane];
        half2_t s01 = h2cast(hv.x), s23 = h2cast(hv.y);
        acc0 = ws0 * (float)s01[0];
        acc1 = ws1 * (float)s01[1];
        acc2 = ws2 * (float)s23[0];
        acc3 = ws3 * (float)s23[1];
    }

    const int nfull = dg & ~7;
    int k = 0;
    for (; k < nfull; k += 8) {
        i32x4 rr[8];
        #pragma unroll
        for (int j = 0; j < 8; j++)
            rr[j] = __builtin_nontemporal_load(recs + beg + k + j);
        uint2 hv[8];
        #pragma unroll
        for (int j = 0; j < 8; j++)
            hv[j] = hh2[(size_t)rr[j].x * D + lane];
        #pragma unroll
        for (int j = 0; j < 8; j += 2)
            edge_pair(rr[j], rr[j + 1], hv[j], hv[j + 1],
                      den0, den1, den2, den3, acc0, acc1, acc2, acc3);
    }
    if (k < dg) {  // clamped 8-wide final iteration (invalid edges get w=0)
        i32x4 rr[8];
        #pragma unroll
        for (int j = 0; j < 8; j++) {
            int kk = min(k + j, dg - 1);
            i32x4 r = __builtin_nontemporal_load(recs + beg + kk);
            if (k + j >= dg) { r.z = 0; r.w = 0; }
            rr[j] = r;
        }
        uint2 hv[8];
        #pragma unroll
        for (int j = 0; j < 8; j++)
            hv[j] = hh2[(size_t)rr[j].x * D + lane];
        #pragma unroll
        for (int j = 0; j < 8; j += 2)
            edge_pair(rr[j], rr[j + 1], hv[j], hv[j + 1],
                      den0, den1, den2, den3, acc0, acc1, acc2, acc3);
    }

    out[(size_t)i * D + lane] =
        0.25f * (acc0 / den0 + acc1 / den1 + acc2 / den2 + acc3 / den3);
}

// BN stats: per-channel sum & sumsq (channel = idx & 63), block-level
// pre-reduction in LDS then one atomic per channel per block (131K total).
__global__ __launch_bounds__(256) void k_bn_stats(const float* __restrict__ out,
                                                  float* __restrict__ sums,
                                                  int total) {
    const int t = threadIdx.x;
    const int stride = gridDim.x * 256;
    float s = 0.f, sq = 0.f;
    for (int idx = blockIdx.x * 256 + t; idx < total; idx += stride) {
        float v = out[idx];
        s += v;
        sq += v * v;
    }
    __shared__ float ls[256], lq[256];
    ls[t] = s;
    lq[t] = sq;
    __syncthreads();
    if (t < 64) {
        s = ls[t] + ls[t + 64] + ls[t + 128] + ls[t + 192];
        sq = lq[t] + lq[t + 64] + lq[t + 128] + lq[t + 192];
        atomicAdd(&sums[t], s);
        atomicAdd(&sums[64 + t], sq);
    }
}

__global__ __launch_bounds__(256) void k_bn_apply(float* __restrict__ out,
                                                  const float* __restrict__ sums,
                                                  const float* __restrict__ gamma,
                                                  const float* __restrict__ beta,
                                                  int total, float invN) {
    int idx = blockIdx.x * 256 + threadIdx.x;
    if (idx >= total) return;
    int c = idx & 63;
    float mean = sums[c] * invN;
    float var = sums[64 + c] * invN - mean * mean;
    float y = gamma[c] * (out[idx] - mean) * rsqrtf(var + BN_EPS) + beta[c];
    out[idx] = fmaxf(y, 0.f);
}

extern "C" void kernel_launch(void* const* d_in, const int* in_sizes, int n_in,
                              void* d_out, int out_size, void* d_ws, size_t ws_size,
                              hipStream_t stream) {
    const float* x       = (const float*)d_in[0];
    const int*   ei      = (const int*)d_in[1];
    const float* W_lin   = (const float*)d_in[2];
    const float* b_lin   = (const float*)d_in[3];
    const float* prelu_w = (const float*)d_in[4];
    const float* W_gat   = (const float*)d_in[5];
    const float* att_src = (const float*)d_in[6];
    const float* att_dst = (const float*)d_in[7];
    // d_in[8] = gat_bias: constant per-channel shift cancelled exactly by BN
    // mean-subtraction -> skipped.
    const float* bn_gamma = (const float*)d_in[9];
    const float* bn_beta  = (const float*)d_in[10];
    float* out = (float*)d_out;

    const int N = in_sizes[0] / D;
    const int E = in_sizes[1] / 2;

    // workspace carve-up (all chunk sizes multiples of 16B).
    // sums + deg8 + gcount are CONTIGUOUS so one hipMemsetAsync zeroes all.
    char* wp = (char*)d_ws;
    _Float16* hh = (_Float16*)wp;      wp += (size_t)N * D * H * sizeof(_Float16);
    float* asrc  = (float*)wp;          wp += (size_t)N * H * sizeof(float);
    float* adst  = (float*)wp;          wp += (size_t)N * H * sizeof(float);
    char* zero_base = wp;
    float* sums  = (float*)wp;          wp += 2 * D * sizeof(float);
    int* deg8    = (int*)wp;            wp += (size_t)8 * N * sizeof(int);
    int* gcount  = (int*)wp;            wp += 4 * sizeof(int);
    size_t zero_bytes = (size_t)(wp - zero_base);
    int* pref8   = (int*)wp;            wp += (size_t)8 * N * sizeof(int);
    int* deg     = (int*)wp;            wp += (size_t)N * sizeof(int);
    int* offs    = (int*)wp;            wp += (size_t)N * sizeof(int);
    int* rank    = (int*)wp;            wp += (size_t)E * sizeof(int);
    i32x4* recs  = (i32x4*)wp;          wp += ((size_t)E + 4) * sizeof(i32x4);
    (void)ws_size; (void)n_in; (void)out_size;

    const int total = N * D;
    const int NB = (N + 255) / 256;
    const int NB1 = (N + 31) / 32;   // k_node grid size (edge-group pivot)

    hipMemsetAsync(zero_base, 0, zero_bytes, stream);
    hipLaunchKernelGGL(k_node, dim3(NB1), dim3(256), 0, stream,
                       x, W_lin, b_lin, prelu_w, W_gat, att_src, att_dst,
                       hh, asrc, adst, ei, deg8, rank, N, E);
    hipLaunchKernelGGL(k_offsets, dim3(NB), dim3(256), 0, stream,
                       deg8, pref8, deg, gcount, offs, N);
    hipLaunchKernelGGL(k_fill, dim3((E + 255) / 256), dim3(256), 0, stream,
                       ei, offs, pref8, rank, asrc, adst, recs, N, E, NB1);
    hipLaunchKernelGGL(k_agg, dim3((N + 3) / 4), dim3(256), 0, stream,
                       asrc, adst, offs, deg, recs, (const uint2*)hh, out, N);
    hipLaunchKernelGGL(k_bn_stats, dim3(1024), dim3(256), 0, stream,
                       out, sums, total);
    hipLaunchKernelGGL(k_bn_apply, dim3((total + 255) / 256), dim3(256), 0, stream,
                       out, sums, bn_gamma, bn_beta, total, 1.f / (float)N);
}

// Round 4
// 257.748 us; speedup vs baseline: 1.0191x; 1.0191x over previous
//
#include <hip/hip_runtime.h>
#include <hip/hip_fp16.h>

#define NEG_SLOPE 0.2f
#define BN_EPS 1e-5f

constexpr int D = 64;   // feature dim
constexpr int H = 4;    // heads
// bucket = dst >> 5 (32 nodes/bucket). LDS histogram arrays sized for
// NBUK <= 1600 (N <= 51200). N = 50000 -> NBUK = 1563.
constexpr int MAXBUK = 1600;

typedef _Float16 half2_t __attribute__((ext_vector_type(2)));
typedef _Float16 half4_t __attribute__((ext_vector_type(4)));
typedef _Float16 half8_t __attribute__((ext_vector_type(8)));
typedef float f32x4_t __attribute__((ext_vector_type(4)));
typedef int i32x4 __attribute__((ext_vector_type(4)));  // native vec for nontemporal builtins

// 16-B edge record: {src, dst, w[4]}; w = per-edge softmax numerators (4 heads)
union Rec {
    i32x4 i4;
    struct { int idx; int pad; half4_t w; } f;
};

#define MFMA16(a, b, c) __builtin_amdgcn_mfma_f32_16x16x32_f16(a, b, c, 0, 0, 0)

#if __has_builtin(__builtin_amdgcn_fdot2)
#define FDOT2(a, b, c) __builtin_amdgcn_fdot2((a), (b), (c), false)
#else
#define FDOT2(a, b, c) ((c) + (float)(a)[0] * (float)(b)[0] + (float)(a)[1] * (float)(b)[1])
#endif

__device__ inline half2_t h2cast(unsigned int u) { return __builtin_bit_cast(half2_t, u); }

__device__ inline float lrelu(float v) { return (v >= 0.f) ? v : NEG_SLOPE * v; }

// load 8 consecutive fp32, split into fp16 hi + lo halves (hi+lo ~ fp32)
__device__ inline void split8(const float* p, bool ok, half8_t& hi, half8_t& lo) {
    float f[8];
    if (ok) {
        float4 a = *(const float4*)p;
        float4 b = *(const float4*)(p + 4);
        f[0] = a.x; f[1] = a.y; f[2] = a.z; f[3] = a.w;
        f[4] = b.x; f[5] = b.y; f[6] = b.z; f[7] = b.w;
    } else {
        #pragma unroll
        for (int j = 0; j < 8; j++) f[j] = 0.f;
    }
    #pragma unroll
    for (int j = 0; j < 8; j++) {
        _Float16 h = (_Float16)f[j];
        hi[j] = h;
        lo[j] = (_Float16)(f[j] - (float)h);
    }
}

// Fused MFMA node kernel, 32 nodes/block — PURE GEMM now.
// ROUND-4: the histogram/rank prelude is REMOVED. R3 counters proved the
// 800K device-scope atomics are serviced MEMORY-SIDE (WRITE_SIZE excess =
// 800K x 32B exactly; slice locality changed nothing) at ~12.5 G/s -> the
// whole kernel drained at the atomic service rate (64 us) with every pipe
// idle. CSR construction moved to an atomic-free (LDS-only) counting sort.
// x1 = prelu(x @ W_lin^T + b_lin); h = x1 @ W_gat^T (split-fp16 MFMA ~
// fp32); h stored fp16 [n][d][head]; att dots from regs.
__global__ __launch_bounds__(256) void k_node(
    const float* __restrict__ x,
    const float* __restrict__ W_lin, const float* __restrict__ b_lin,
    const float* __restrict__ prelu_w, const float* __restrict__ W_gat,
    const float* __restrict__ att_src, const float* __restrict__ att_dst,
    _Float16* __restrict__ hh, float* __restrict__ asrc_ws,
    float* __restrict__ adst_ws, int N)
{
    __shared__ _Float16 smem[32 * 264];   // 16.9 KB total (h_lds aliases x1)
    _Float16* __restrict__ h_lds = smem;           // [32][264] after re-barrier
    _Float16* __restrict__ x1hi  = smem;           // [32][72]
    _Float16* __restrict__ x1lo  = smem + 32 * 72; // [32][72]

    const int t = threadIdx.x;
    const int w = t >> 6;    // wave id == head
    const int l = t & 63;
    const int li = l & 15;
    const int lq = l >> 4;
    const int base = blockIdx.x * 32;
    const int nvalid = min(32, N - base);

    // ---- stage A: MFMA x @ W_lin^T for cols 16w..16w+15, 2 m-tiles ----
    f32x4_t accA[2] = {};
    {
        half8_t blh[2], bll[2];
        const int n = 16 * w + li;
        #pragma unroll
        for (int ks = 0; ks < 2; ks++)
            split8(W_lin + n * 64 + 32 * ks + 8 * lq, true, blh[ks], bll[ks]);
        #pragma unroll
        for (int mt = 0; mt < 2; mt++) {
            const int row = base + 16 * mt + li;
            const bool ok = row < N;
            #pragma unroll
            for (int ks = 0; ks < 2; ks++) {
                half8_t ah, al;
                split8(x + (size_t)row * 64 + 32 * ks + 8 * lq, ok, ah, al);
                accA[mt] = MFMA16(ah, blh[ks], accA[mt]);
                accA[mt] = MFMA16(al, blh[ks], accA[mt]);
                accA[mt] = MFMA16(ah, bll[ks], accA[mt]);
            }
        }
    }

    // epilogue A: +bias, prelu, split to fp16 hi/lo in LDS
    {
        const int n = 16 * w + li;
        const float bl = b_lin[n];
        const float pw = prelu_w[n];
        #pragma unroll
        for (int mt = 0; mt < 2; mt++) {
            #pragma unroll
            for (int r = 0; r < 4; r++) {
                const int m = 16 * mt + lq * 4 + r;
                float v = accA[mt][r] + bl;
                v = (v >= 0.f) ? v : pw * v;
                _Float16 hi = (_Float16)v;
                x1hi[m * 72 + n] = hi;
                x1lo[m * 72 + n] = (_Float16)(v - (float)hi);
            }
        }
    }
    __syncthreads();

    // ---- stage B: MFMA x1 @ W_gat^T for cols 64w..64w+63, 2 m-tiles ----
    half8_t xah[2][2], xal[2][2];
    #pragma unroll
    for (int mt = 0; mt < 2; mt++) {
        #pragma unroll
        for (int ks = 0; ks < 2; ks++) {
            const int off = (16 * mt + li) * 72 + 32 * ks + 8 * lq;
            xah[mt][ks] = *(const half8_t*)(&x1hi[off]);
            xal[mt][ks] = *(const half8_t*)(&x1lo[off]);
        }
    }
    f32x4_t accB[2][4] = {};
    #pragma unroll
    for (int nt = 0; nt < 4; nt++) {
        half8_t wh[2], wl[2];
        const int c = 64 * w + 16 * nt + li;
        #pragma unroll
        for (int ks = 0; ks < 2; ks++)
            split8(W_gat + (size_t)c * 64 + 32 * ks + 8 * lq, true, wh[ks], wl[ks]);
        #pragma unroll
        for (int mt = 0; mt < 2; mt++) {
            #pragma unroll
            for (int ks = 0; ks < 2; ks++) {
                accB[mt][nt] = MFMA16(xah[mt][ks], wh[ks], accB[mt][nt]);
                accB[mt][nt] = MFMA16(xal[mt][ks], wh[ks], accB[mt][nt]);
                accB[mt][nt] = MFMA16(xah[mt][ks], wl[ks], accB[mt][nt]);
            }
        }
    }

    // ---- attention dots from registers: a[n][w] = sum_d h[n][w][d]*att[w][d]
    {
        float asv[4], adv[4];
        #pragma unroll
        for (int nt = 0; nt < 4; nt++) {
            const int c = 64 * w + 16 * nt + li;
            asv[nt] = att_src[c];
            adv[nt] = att_dst[c];
        }
        #pragma unroll
        for (int mt = 0; mt < 2; mt++) {
            #pragma unroll
            for (int r = 0; r < 4; r++) {
                float s = 0.f, dsum = 0.f;
                #pragma unroll
                for (int nt = 0; nt < 4; nt++) {
                    s += accB[mt][nt][r] * asv[nt];
                    dsum += accB[mt][nt][r] * adv[nt];
                }
                #pragma unroll
                for (int off = 1; off < 16; off <<= 1) {
                    s += __shfl_xor(s, off, 64);
                    dsum += __shfl_xor(dsum, off, 64);
                }
                if (li == 0) {
                    const int m = 16 * mt + lq * 4 + r;
                    if (m < nvalid) {
                        asrc_ws[(size_t)(base + m) * H + w] = s;
                        adst_ws[(size_t)(base + m) * H + w] = dsum;
                    }
                }
            }
        }
    }

    // WAR guard: all waves must finish their x1 ds_reads before h_lds
    // (same LDS bytes) is overwritten.
    __syncthreads();

    // ---- h -> LDS in padded [m][264] layout, then coalesced global write ----
    #pragma unroll
    for (int mt = 0; mt < 2; mt++) {
        #pragma unroll
        for (int nt = 0; nt < 4; nt++) {
            #pragma unroll
            for (int r = 0; r < 4; r++) {
                const int m = 16 * mt + lq * 4 + r;
                const int d = 16 * nt + li;
                h_lds[m * 264 + d * 4 + w] = (_Float16)accB[mt][nt][r];
            }
        }
    }
    __syncthreads();
    {
        const int chunks = nvalid * 32;  // 8 halves (16B) per chunk
        const uint4* src = (const uint4*)h_lds;
        uint4* dst = (uint4*)(hh + (size_t)base * 256);
        for (int i = t; i < chunks; i += 256) {
            int row = i >> 5;
            int col = i & 31;
            dst[i] = src[row * 33 + col];  // padded row = 33 uint4
        }
    }
}

// ---- atomic-free CSR build: two-level counting sort, LDS atomics only ----
// Pass 1: per-block (p = 0..255, contiguous edge chunk) LDS histogram over
// buckets (bucket = dst>>5), dumped to gcnt[b][p] (bucket-major).
__global__ __launch_bounds__(256) void k_hist(const int* __restrict__ ei,
                                              int* __restrict__ gcnt,
                                              int E, int chunk, int NBUK) {
    __shared__ int cnt[MAXBUK];
    const int p = blockIdx.x;
    const int t = threadIdx.x;
    for (int b = t; b < NBUK; b += 256) cnt[b] = 0;
    __syncthreads();
    const int e0 = p * chunk;
    const int e1 = min(E, e0 + chunk);
    for (int e = e0 + t; e < e1; e += 256) {
        int d = ei[E + e];
        atomicAdd(&cnt[d >> 5], 1);
    }
    __syncthreads();
    for (int b = t; b < NBUK; b += 256) gcnt[(size_t)b * 256 + p] = cnt[b];
}

// scan stage 1: per-bucket totals (one wave per bucket, 256 contiguous ints)
__global__ __launch_bounds__(256) void k_scan1(const int* __restrict__ gcnt,
                                               int* __restrict__ tot, int NBUK) {
    const int b = blockIdx.x * 4 + (threadIdx.x >> 6);
    const int l = threadIdx.x & 63;
    if (b >= NBUK) return;
    int4 v = ((const int4*)(gcnt + (size_t)b * 256))[l];
    int s = v.x + v.y + v.z + v.w;
    #pragma unroll
    for (int off = 1; off < 64; off <<= 1) s += __shfl_xor(s, off, 64);
    if (l == 0) tot[b] = s;
}

// scan stage 2: exclusive scan of bucket totals -> base[b]; base[NBUK] = E.
__global__ __launch_bounds__(256) void k_scan2(const int* __restrict__ tot,
                                               int* __restrict__ base, int NBUK) {
    __shared__ int sm[256];
    __shared__ int carry_s;
    const int t = threadIdx.x;
    if (t == 0) carry_s = 0;
    __syncthreads();
    for (int c0 = 0; c0 < NBUK; c0 += 256) {
        const int i = c0 + t;
        const int v = (i < NBUK) ? tot[i] : 0;
        sm[t] = v;
        __syncthreads();
        for (int off = 1; off < 256; off <<= 1) {
            int u = (t >= off) ? sm[t - off] : 0;
            __syncthreads();
            sm[t] += u;
            __syncthreads();
        }
        const int inc = sm[t];
        const int cc = carry_s;
        __syncthreads();
        if (t == 255) carry_s = cc + sm[255];
        if (i < NBUK) base[i] = cc + inc - v;
        __syncthreads();
    }
    if (t == 0) base[NBUK] = carry_s;
}

// scan stage 3: gcnt[b][p] <- base[b] + exclusive_scan_p(gcnt[b][.])
__global__ __launch_bounds__(256) void k_scan3(int* __restrict__ gcnt,
                                               const int* __restrict__ base,
                                               int NBUK) {
    const int b = blockIdx.x * 4 + (threadIdx.x >> 6);
    const int l = threadIdx.x & 63;
    if (b >= NBUK) return;
    int4 v = ((int4*)(gcnt + (size_t)b * 256))[l];
    int s = v.x + v.y + v.z + v.w;
    int inc = s;
    #pragma unroll
    for (int off = 1; off < 64; off <<= 1) {
        int u = __shfl_up(inc, off, 64);
        if (l >= off) inc += u;
    }
    int ex = base[b] + inc - s;
    int4 o;
    o.x = ex;
    o.y = ex + v.x;
    o.z = o.y + v.y;
    o.w = o.z + v.z;
    ((int4*)(gcnt + (size_t)b * 256))[l] = o;
}

// Pass 2: re-walk the same chunks; LDS cursor gives each edge a unique rank
// within (bucket, block); pos = gcnt[b][p] + rank. Computes the softmax
// numerators w from the L2-resident asrc/adst tables. recsA is bucket-
// grouped (mixed nodes within a bucket); dst carried in the pad field.
__global__ __launch_bounds__(256) void k_fillB(const int* __restrict__ ei,
                                               const int* __restrict__ gcnt,
                                               const float* __restrict__ asrc,
                                               const float* __restrict__ adst,
                                               i32x4* __restrict__ recsA,
                                               int E, int chunk, int NBUK) {
    __shared__ int cur[MAXBUK];
    const int p = blockIdx.x;
    const int t = threadIdx.x;
    for (int b = t; b < NBUK; b += 256) cur[b] = 0;
    __syncthreads();
    const int e0 = p * chunk;
    const int e1 = min(E, e0 + chunk);
    for (int e = e0 + t; e < e1; e += 256) {
        int s = ei[e];
        int d = ei[E + e];
        int b = d >> 5;
        int lr = atomicAdd(&cur[b], 1);
        int pos = gcnt[(size_t)b * 256 + p] + lr;
        float4 a = *(const float4*)(asrc + (size_t)s * H);
        float4 bb = *(const float4*)(adst + (size_t)d * H);
        Rec r;
        r.f.idx = s;
        r.f.pad = d;
        r.f.w[0] = (_Float16)__expf(lrelu(a.x + bb.x));
        r.f.w[1] = (_Float16)__expf(lrelu(a.y + bb.y));
        r.f.w[2] = (_Float16)__expf(lrelu(a.z + bb.z));
        r.f.w[3] = (_Float16)__expf(lrelu(a.w + bb.w));
        recsA[pos] = r.i4;
    }
}

// Pass 3: one block per bucket regroups its ~512 edges by node (LDS count /
// scan / place) into the final CSR recsB, and writes offs/deg per node.
__global__ __launch_bounds__(256) void k_fillC(const i32x4* __restrict__ recsA,
                                               const int* __restrict__ base,
                                               i32x4* __restrict__ recsB,
                                               int* __restrict__ offs,
                                               int* __restrict__ deg,
                                               int N, int NBUK) {
    const int b = blockIdx.x;
    const int t = threadIdx.x;
    __shared__ int c32[32], s32[32], cu32[32];
    const int lo = base[b];
    const int hi = base[b + 1];
    if (t < 32) { c32[t] = 0; cu32[t] = 0; }
    __syncthreads();
    for (int i = lo + t; i < hi; i += 256) {
        Rec r;
        r.i4 = recsA[i];
        atomicAdd(&c32[r.f.pad & 31], 1);
    }
    __syncthreads();
    if (t < 32) {
        int v = c32[t];
        int inc = v;
        #pragma unroll
        for (int off = 1; off < 32; off <<= 1) {
            int u = __shfl_up(inc, off, 64);
            if (t >= off) inc += u;
        }
        s32[t] = lo + inc - v;
        int node = b * 32 + t;
        if (node < N) {
            offs[node] = lo + inc - v;
            deg[node] = v;
        }
    }
    __syncthreads();
    for (int i = lo + t; i < hi; i += 256) {
        Rec r;
        r.i4 = recsA[i];
        int n = r.f.pad & 31;
        int slot = atomicAdd(&cu32[n], 1);
        recsB[s32[n] + slot] = r.i4;
    }
}

// process one edge pair (A,B) with packed fp16 math:
// v_perm builds (wA_h, wB_h) / (hA_h, hB_h) half2 pairs, v_dot2_f32_f16
// does den_h += wA+wB and acc_h += wA*hA + wB*hB (fp16 mul, fp32 accum --
// numerically identical to the old cvt+fma path, half the VALU ops).
__device__ inline void edge_pair(const i32x4 ra, const i32x4 rb,
                                 const uint2 ha, const uint2 hb,
                                 float& den0, float& den1, float& den2, float& den3,
                                 float& acc0, float& acc1, float& acc2, float& acc3)
{
    const half2_t one2 = h2cast(0x3C003C00u);
    unsigned int wp0 = __builtin_amdgcn_perm((unsigned int)rb.z, (unsigned int)ra.z, 0x05040100u);
    unsigned int wp1 = __builtin_amdgcn_perm((unsigned int)rb.z, (unsigned int)ra.z, 0x07060302u);
    unsigned int wp2 = __builtin_amdgcn_perm((unsigned int)rb.w, (unsigned int)ra.w, 0x05040100u);
    unsigned int wp3 = __builtin_amdgcn_perm((unsigned int)rb.w, (unsigned int)ra.w, 0x07060302u);
    unsigned int hp0 = __builtin_amdgcn_perm(hb.x, ha.x, 0x05040100u);
    unsigned int hp1 = __builtin_amdgcn_perm(hb.x, ha.x, 0x07060302u);
    unsigned int hp2 = __builtin_amdgcn_perm(hb.y, ha.y, 0x05040100u);
    unsigned int hp3 = __builtin_amdgcn_perm(hb.y, ha.y, 0x07060302u);
    den0 = FDOT2(h2cast(wp0), one2, den0);
    den1 = FDOT2(h2cast(wp1), one2, den1);
    den2 = FDOT2(h2cast(wp2), one2, den2);
    den3 = FDOT2(h2cast(wp3), one2, den3);
    acc0 = FDOT2(h2cast(wp0), h2cast(hp0), acc0);
    acc1 = FDOT2(h2cast(wp1), h2cast(hp1), acc1);
    acc2 = FDOT2(h2cast(wp2), h2cast(hp2), acc2);
    acc3 = FDOT2(h2cast(wp3), h2cast(hp3), acc3);
}

// ---- fused softmax + aggregation: one wave per dst node ----
// 8-wide unrolled gather loop (8 recs + 8 h-rows in flight per wave) with a
// CLAMPED final iteration (w zeroed for k>=deg) -- no serial 1-wide tail
// whose dependent rec->gather chains were pure latency. recs are streamed
// once -> nontemporal loads keep them from evicting the 16x-reused hh lines.
// NO BN-stat atomics here: round-1 showed 6.4M contended atomics onto 64
// cache lines throttle the kernel 2.6x (atomic-serialization floor).
__global__ __launch_bounds__(256) void k_agg(
    const float* __restrict__ asrc, const float* __restrict__ adst,
    const int* __restrict__ offs, const int* __restrict__ deg,
    const i32x4* __restrict__ recs, const uint2* __restrict__ hh2,
    float* __restrict__ out, int N)
{
    int wid = (blockIdx.x * 256 + threadIdx.x) >> 6;
    int lane = threadIdx.x & 63;
    if (wid >= N) return;
    const int i = wid;

    float4 b = *(const float4*)(adst + (size_t)i * H);
    float4 a0 = *(const float4*)(asrc + (size_t)i * H);
    float ws0 = __expf(lrelu(a0.x + b.x));
    float ws1 = __expf(lrelu(a0.y + b.y));
    float ws2 = __expf(lrelu(a0.z + b.z));
    float ws3 = __expf(lrelu(a0.w + b.w));

    const int beg = __builtin_amdgcn_readfirstlane(offs[i]);
    const int dg  = __builtin_amdgcn_readfirstlane(deg[i]);

    // self-loop contribution
    float den0 = ws0, den1 = ws1, den2 = ws2, den3 = ws3;
    float acc0, acc1, acc2, acc3;
    {
        uint2 hv = hh2[(size_t)i * D + lane];
        half2_t s01 = h2cast(hv.x), s23 = h2cast(hv.y);
        acc0 = ws0 * (float)s01[0];
        acc1 = ws1 * (float)s01[1];
        acc2 = ws2 * (float)s23[0];
        acc3 = ws3 * (float)s23[1];
    }

    const int nfull = dg & ~7;
    int k = 0;
    for (; k < nfull; k += 8) {
        i32x4 rr[8];
        #pragma unroll
        for (int j = 0; j < 8; j++)
            rr[j] = __builtin_nontemporal_load(recs + beg + k + j);
        uint2 hv[8];
        #pragma unroll
        for (int j = 0; j < 8; j++)
            hv[j] = hh2[(size_t)rr[j].x * D + lane];
        #pragma unroll
        for (int j = 0; j < 8; j += 2)
            edge_pair(rr[j], rr[j + 1], hv[j], hv[j + 1],
                      den0, den1, den2, den3, acc0, acc1, acc2, acc3);
    }
    if (k < dg) {  // clamped 8-wide final iteration (invalid edges get w=0)
        i32x4 rr[8];
        #pragma unroll
        for (int j = 0; j < 8; j++) {
            int kk = min(k + j, dg - 1);
            i32x4 r = __builtin_nontemporal_load(recs + beg + kk);
            if (k + j >= dg) { r.z = 0; r.w = 0; }
            rr[j] = r;
        }
        uint2 hv[8];
        #pragma unroll
        for (int j = 0; j < 8; j++)
            hv[j] = hh2[(size_t)rr[j].x * D + lane];
        #pragma unroll
        for (int j = 0; j < 8; j += 2)
            edge_pair(rr[j], rr[j + 1], hv[j], hv[j + 1],
                      den0, den1, den2, den3, acc0, acc1, acc2, acc3);
    }

    out[(size_t)i * D + lane] =
        0.25f * (acc0 / den0 + acc1 / den1 + acc2 / den2 + acc3 / den3);
}

// BN stats: per-channel sum & sumsq (channel = idx & 63), block-level
// pre-reduction in LDS then one atomic per channel per block (131K total).
__global__ __launch_bounds__(256) void k_bn_stats(const float* __restrict__ out,
                                                  float* __restrict__ sums,
                                                  int total) {
    const int t = threadIdx.x;
    const int stride = gridDim.x * 256;
    float s = 0.f, sq = 0.f;
    for (int idx = blockIdx.x * 256 + t; idx < total; idx += stride) {
        float v = out[idx];
        s += v;
        sq += v * v;
    }
    __shared__ float ls[256], lq[256];
    ls[t] = s;
    lq[t] = sq;
    __syncthreads();
    if (t < 64) {
        s = ls[t] + ls[t + 64] + ls[t + 128] + ls[t + 192];
        sq = lq[t] + lq[t + 64] + lq[t + 128] + lq[t + 192];
        atomicAdd(&sums[t], s);
        atomicAdd(&sums[64 + t], sq);
    }
}

__global__ __launch_bounds__(256) void k_bn_apply(float* __restrict__ out,
                                                  const float* __restrict__ sums,
                                                  const float* __restrict__ gamma,
                                                  const float* __restrict__ beta,
                                                  int total, float invN) {
    int idx = blockIdx.x * 256 + threadIdx.x;
    if (idx >= total) return;
    int c = idx & 63;
    float mean = sums[c] * invN;
    float var = sums[64 + c] * invN - mean * mean;
    float y = gamma[c] * (out[idx] - mean) * rsqrtf(var + BN_EPS) + beta[c];
    out[idx] = fmaxf(y, 0.f);
}

extern "C" void kernel_launch(void* const* d_in, const int* in_sizes, int n_in,
                              void* d_out, int out_size, void* d_ws, size_t ws_size,
                              hipStream_t stream) {
    const float* x       = (const float*)d_in[0];
    const int*   ei      = (const int*)d_in[1];
    const float* W_lin   = (const float*)d_in[2];
    const float* b_lin   = (const float*)d_in[3];
    const float* prelu_w = (const float*)d_in[4];
    const float* W_gat   = (const float*)d_in[5];
    const float* att_src = (const float*)d_in[6];
    const float* att_dst = (const float*)d_in[7];
    // d_in[8] = gat_bias: constant per-channel shift cancelled exactly by BN
    // mean-subtraction -> skipped.
    const float* bn_gamma = (const float*)d_in[9];
    const float* bn_beta  = (const float*)d_in[10];
    float* out = (float*)d_out;

    const int N = in_sizes[0] / D;
    const int E = in_sizes[1] / 2;
    const int NBUK = (N + 31) / 32;        // <= MAXBUK (N=50000 -> 1563)
    const int chunk = (E + 255) / 256;     // edges per hist/fill block

    // workspace carve-up (all chunk sizes multiples of 16B).
    char* wp = (char*)d_ws;
    _Float16* hh = (_Float16*)wp;      wp += (size_t)N * D * H * sizeof(_Float16);
    float* asrc  = (float*)wp;          wp += (size_t)N * H * sizeof(float);
    float* adst  = (float*)wp;          wp += (size_t)N * H * sizeof(float);
    float* sums  = (float*)wp;          wp += 2 * D * sizeof(float);
    int* gcnt    = (int*)wp;            wp += (size_t)NBUK * 256 * sizeof(int);
    int* tot     = (int*)wp;            wp += (size_t)((NBUK + 3) & ~3) * sizeof(int);
    int* basep   = (int*)wp;            wp += (size_t)((NBUK + 4) & ~3) * sizeof(int);
    int* offs    = (int*)wp;            wp += (size_t)N * sizeof(int);
    int* deg     = (int*)wp;            wp += (size_t)N * sizeof(int);
    i32x4* recsB = (i32x4*)wp;          wp += (size_t)E * sizeof(i32x4);
    // recsA (bucket-grouped intermediate) aliases d_out: dead before k_agg
    // writes out. Falls back to workspace if out is too small.
    i32x4* recsA;
    if ((size_t)E * sizeof(i32x4) <= (size_t)out_size) {
        recsA = (i32x4*)d_out;
    } else {
        recsA = (i32x4*)wp;             wp += (size_t)E * sizeof(i32x4);
    }
    (void)ws_size; (void)n_in;

    const int total = N * D;
    const int NB1 = (N + 31) / 32;     // k_node grid
    const int NBW = (NBUK + 3) / 4;    // wave-per-bucket grids

    hipMemsetAsync(sums, 0, 2 * D * sizeof(float), stream);
    hipLaunchKernelGGL(k_node, dim3(NB1), dim3(256), 0, stream,
                       x, W_lin, b_lin, prelu_w, W_gat, att_src, att_dst,
                       hh, asrc, adst, N);
    hipLaunchKernelGGL(k_hist, dim3(256), dim3(256), 0, stream,
                       ei, gcnt, E, chunk, NBUK);
    hipLaunchKernelGGL(k_scan1, dim3(NBW), dim3(256), 0, stream,
                       gcnt, tot, NBUK);
    hipLaunchKernelGGL(k_scan2, dim3(1), dim3(256), 0, stream,
                       tot, basep, NBUK);
    hipLaunchKernelGGL(k_scan3, dim3(NBW), dim3(256), 0, stream,
                       gcnt, basep, NBUK);
    hipLaunchKernelGGL(k_fillB, dim3(256), dim3(256), 0, stream,
                       ei, gcnt, asrc, adst, recsA, E, chunk, NBUK);
    hipLaunchKernelGGL(k_fillC, dim3(NBUK), dim3(256), 0, stream,
                       recsA, basep, recsB, offs, deg, N, NBUK);
    hipLaunchKernelGGL(k_agg, dim3((N + 3) / 4), dim3(256), 0, stream,
                       asrc, adst, offs, deg, recsB, (const uint2*)hh, out, N);
    hipLaunchKernelGGL(k_bn_stats, dim3(1024), dim3(256), 0, stream,
                       out, sums, total);
    hipLaunchKernelGGL(k_bn_apply, dim3((total + 255) / 256), dim3(256), 0, stream,
                       out, sums, bn_gamma, bn_beta, total, 1.f / (float)N);
}